// Round 10
// baseline (305.444 us; speedup 1.0000x reference)
//
#include <hip/hip_runtime.h>
#include <hip/hip_bf16.h>
#include <stdint.h>

typedef __attribute__((ext_vector_type(8))) short short8;  // 8 bf16 (4 VGPRs)
typedef __attribute__((ext_vector_type(4))) float f32x4;   // 4 fp32 acc

__device__ __forceinline__ uint16_t f2bf(float f) {
    union { float f; uint32_t u; } v; v.f = f;
    uint32_t r = v.u + 0x7FFF + ((v.u >> 16) & 1);  // RNE
    return (uint16_t)(r >> 16);
}
__device__ __forceinline__ float bf2f(uint16_t u) {
    union { uint32_t u; float f; } v; v.u = ((uint32_t)u) << 16;
    return v.f;
}

template<int F32>
__device__ __forceinline__ uint4 load8(const void* p, size_t off) {
    if (F32) {
        const float* f = (const float*)p + off;
        float4 f0 = *(const float4*)f;
        float4 f1 = *(const float4*)(f + 4);
        uint4 r;
        r.x = (uint32_t)f2bf(f0.x) | ((uint32_t)f2bf(f0.y) << 16);
        r.y = (uint32_t)f2bf(f0.z) | ((uint32_t)f2bf(f0.w) << 16);
        r.z = (uint32_t)f2bf(f1.x) | ((uint32_t)f2bf(f1.y) << 16);
        r.w = (uint32_t)f2bf(f1.z) | ((uint32_t)f2bf(f1.w) << 16);
        return r;
    } else {
        return *(const uint4*)((const uint16_t*)p + off);
    }
}

// global -> LDS direct DMA, 16 B/lane; LDS dest = wave-uniform base + lane*16.
#define GLDS(gp, lp) __builtin_amdgcn_global_load_lds( \
    (const __attribute__((address_space(1))) void*)(gp), \
    (__attribute__((address_space(3))) void*)(lp), 16, 0, 0)

// ---------------------------------------------------------------------------
// cvt (weights + pos only now) + mask canonicalization fused. Block 0 also
// canonicalizes the bool mask (encoding auto-detected).
// ---------------------------------------------------------------------------
struct CvtSeg { const float* s; uint16_t* d; int n8; };
struct CvtArgs { CvtSeg seg[6]; int nseg; const void* mraw; int* mcanon; };

__global__ __launch_bounds__(256) void cvt_bf16(CvtArgs a)
{
    if (blockIdx.x == 0) {
        __shared__ int flags[3];
        const uint32_t* w = (const uint32_t*)a.mraw;
        const uint8_t* b8 = (const uint8_t*)a.mraw;
        const int t = threadIdx.x;
        if (t < 3) flags[t] = 0;
        __syncthreads();
        int fbyte = 0, ff32 = 0, fodd = 0;
        for (int i = t; i < 1024; i += 256) {
            uint32_t v = w[i];
            if (v != 0u && v != 1u && v != 0x3F800000u) fbyte = 1;
            if (v == 0x3F800000u) ff32 = 1;
            if ((i & 1) && v != 0u) fodd = 1;
        }
        if (fbyte) atomicOr(&flags[0], 1);
        if (ff32)  atomicOr(&flags[1], 1);
        if (fodd)  atomicOr(&flags[2], 1);
        __syncthreads();
        int mode;  // 0 = word, 1 = byte, 2 = int64
        if (flags[0]) mode = 1;
        else if (flags[1]) mode = 0;
        else if (!flags[2]) mode = 2;
        else mode = 0;
        for (int k = t; k < 4096; k += 256) {
            int val;
            if (mode == 1)      val = (b8[k] != 0);
            else if (mode == 2) val = (w[2 * k] != 0u);
            else                val = (w[k] != 0u);
            a.mcanon[k] = val;
        }
    }
    const int tid = blockIdx.x * 256 + threadIdx.x;
    const int stride = gridDim.x * 256;
    for (int s = 0; s < a.nseg; ++s) {
        const float* src = a.seg[s].s;
        uint16_t* dst = a.seg[s].d;
        const int n8 = a.seg[s].n8;
        if (src) {
            for (int i = tid; i < n8; i += stride)
                *(uint4*)(dst + (size_t)i * 8) = load8<1>(src, (size_t)i * 8);
        } else {
            const uint4 z = {0u, 0u, 0u, 0u};
            for (int i = tid; i < n8; i += stride)
                *(uint4*)(dst + (size_t)i * 8) = z;
        }
    }
}

// ---------------------------------------------------------------------------
// QKV GEMM, 128x128 tile: A is fp32 staged DIRECTLY via global_load_lds into
// a 16KB LDS tile (4 floats/lane), converted to bf16 at fragment build.
// Removes the x pre-convert pass and the unverifiable ws-size branch; x is
// read exactly once from HBM. B (weights, bf16) staged via glds as before.
// cm 1: (B,H,T,DH); cm 2: (B,H,DH,T) via per-wave LDS transpose.
// ---------------------------------------------------------------------------
__global__ __launch_bounds__(256) void gemm128_qkv(
    const float* __restrict__ xq, const float* __restrict__ xk, const float* __restrict__ xv,
    const uint16_t* __restrict__ Wq, const uint16_t* __restrict__ Wk, const uint16_t* __restrict__ Wv,
    uint16_t* __restrict__ Qh, uint16_t* __restrict__ Khd, uint16_t* __restrict__ Vt)
{
    __shared__ alignas(16) float    AsF[128 * 32];   // 16 KB fp32 A tile
    __shared__ alignas(16) uint16_t Bs[128 * 32];    // 8 KB bf16 B tile

    const int z = blockIdx.z;
    const float* A = (z == 0) ? xq : (z == 1) ? xk : xv;
    const uint16_t* B = (z == 0) ? Wq : (z == 1) ? Wk : Wv;
    uint16_t* C = (z == 0) ? Qh : (z == 1) ? Khd : Vt;
    const int cm = (z == 2) ? 2 : 1;
    const int bm = blockIdx.x, bn = blockIdx.y;
    const int K = 1024;

    const int t = threadIdx.x;
    const int lane = t & 63, wave = t >> 6;
    const int lrow = lane & 15, quad = lane >> 4;
    const int wr = (wave >> 1) * 64, wc = (wave & 1) * 64;

    // B glds map (bf16): row = wave*16 + lane/4, colseg = (lane&3)*8
    const int g_row = wave * 16 + (lane >> 2);
    const int g_col = (lane & 3) * 8;
    // A glds map (fp32): per instr g: row = (wave*4+g)*8 + lane/8, col = (lane&7)*4
    const int a_r = lane >> 3;
    const int a_c = (lane & 7) * 4;

    const f32x4 fz = {0.f, 0.f, 0.f, 0.f};
    f32x4 acc[4][4];
#pragma unroll
    for (int i = 0; i < 4; ++i)
#pragma unroll
        for (int j = 0; j < 4; ++j) acc[i][j] = fz;

    for (int k0 = 0; k0 < K; k0 += 32) {
        __syncthreads();
#pragma unroll
        for (int g = 0; g < 4; ++g) {
            int rbase = (wave * 4 + g) * 8;
            GLDS(A + (size_t)(bm * 128 + rbase + a_r) * K + k0 + a_c,
                 AsF + (size_t)(wave * 4 + g) * 256);
        }
        GLDS(B + (size_t)(bn * 128 + g_row) * K + k0 + g_col,      Bs + wave * 512);
        GLDS(B + (size_t)(bn * 128 + g_row + 64) * K + k0 + g_col, Bs + wave * 512 + 2048);
        __syncthreads();

        short8 a[4], b[4];
#pragma unroll
        for (int i = 0; i < 4; ++i) {
            const float* rp = AsF + (wr + i * 16 + lrow) * 32 + quad * 8;
            float4 f0 = *(const float4*)rp;
            float4 f1 = *(const float4*)(rp + 4);
            uint4 pk;
            pk.x = (uint32_t)f2bf(f0.x) | ((uint32_t)f2bf(f0.y) << 16);
            pk.y = (uint32_t)f2bf(f0.z) | ((uint32_t)f2bf(f0.w) << 16);
            pk.z = (uint32_t)f2bf(f1.x) | ((uint32_t)f2bf(f1.y) << 16);
            pk.w = (uint32_t)f2bf(f1.z) | ((uint32_t)f2bf(f1.w) << 16);
            a[i] = *(short8*)&pk;
        }
#pragma unroll
        for (int j = 0; j < 4; ++j)
            b[j] = *(const short8*)(Bs + (wc + j * 16 + lrow) * 32 + quad * 8);
#pragma unroll
        for (int i = 0; i < 4; ++i)
#pragma unroll
            for (int j = 0; j < 4; ++j)
                acc[i][j] = __builtin_amdgcn_mfma_f32_16x16x32_bf16(a[i], b[j], acc[i][j], 0, 0, 0);
    }

    if (cm == 2) {
        __syncthreads();
        uint16_t* scr = (uint16_t*)AsF + wave * 1024;
#pragma unroll
        for (int i = 0; i < 4; ++i)
#pragma unroll
            for (int j = 0; j < 4; ++j) {
                uint2 pk;
                pk.x = (uint32_t)f2bf(acc[i][j][0]) | ((uint32_t)f2bf(acc[i][j][1]) << 16);
                pk.y = (uint32_t)f2bf(acc[i][j][2]) | ((uint32_t)f2bf(acc[i][j][3]) << 16);
                *(uint2*)(scr + lrow * 16 + quad * 4) = pk;
                if (lane < 32) {
                    int n = lane >> 1, m8 = (lane & 1) * 8;
                    short8 vv = *(const short8*)(scr + n * 16 + m8);
                    int ng = bn * 128 + wc + j * 16 + n;        // (h,d)
                    int hh = ng >> 6, d = ng & 63;
                    int mg = bm * 128 + wr + i * 16;            // t base
                    int bb = mg >> 10, tl = (mg & 1023) + m8;
                    *(short8*)(C + ((((size_t)bb * 16 + hh) * 64 + d) * 1024 + tl)) = vv;
                }
            }
        return;
    }

#pragma unroll
    for (int i = 0; i < 4; ++i)
#pragma unroll
        for (int j = 0; j < 4; ++j)
#pragma unroll
            for (int r = 0; r < 4; ++r) {
                // verified C/D map: row = quad*4 + reg, col = lane&15
                int m = bm * 128 + wr + i * 16 + quad * 4 + r;
                int n = bn * 128 + wc + j * 16 + lrow;
                int bb = m >> 10, tt = m & 1023, hh = n >> 6, d = n & 63;
                C[(((size_t)bb * 16 + hh) * 1024 + tt) * 64 + d] = f2bf(acc[i][j][r]);
            }
}

// ---------------------------------------------------------------------------
// Output-projection GEMM (bf16 A via glds), fp32 row-major C — m97 structure.
// ---------------------------------------------------------------------------
__global__ __launch_bounds__(256) void gemm128_single(
    const uint16_t* __restrict__ A, const uint16_t* __restrict__ B,
    float* __restrict__ C, int M, int N, int K)
{
    __shared__ alignas(16) uint16_t As[128 * 32];
    __shared__ alignas(16) uint16_t Bs[128 * 32];

    const int t = threadIdx.x;
    const int lane = t & 63, wave = t >> 6;
    const int lrow = lane & 15, quad = lane >> 4;
    const int wr = (wave >> 1) * 64, wc = (wave & 1) * 64;
    const int g_row = wave * 16 + (lane >> 2);
    const int g_col = (lane & 3) * 8;
    const int bm = blockIdx.x, bn = blockIdx.y;

    const f32x4 fz = {0.f, 0.f, 0.f, 0.f};
    f32x4 acc[4][4];
#pragma unroll
    for (int i = 0; i < 4; ++i)
#pragma unroll
        for (int j = 0; j < 4; ++j) acc[i][j] = fz;

    for (int k0 = 0; k0 < K; k0 += 32) {
        __syncthreads();
        GLDS(A + (size_t)(bm * 128 + g_row) * K + k0 + g_col,      As + wave * 512);
        GLDS(A + (size_t)(bm * 128 + g_row + 64) * K + k0 + g_col, As + wave * 512 + 2048);
        GLDS(B + (size_t)(bn * 128 + g_row) * K + k0 + g_col,      Bs + wave * 512);
        GLDS(B + (size_t)(bn * 128 + g_row + 64) * K + k0 + g_col, Bs + wave * 512 + 2048);
        __syncthreads();

        short8 a[4], b[4];
#pragma unroll
        for (int i = 0; i < 4; ++i)
            a[i] = *(const short8*)(As + (wr + i * 16 + lrow) * 32 + quad * 8);
#pragma unroll
        for (int j = 0; j < 4; ++j)
            b[j] = *(const short8*)(Bs + (wc + j * 16 + lrow) * 32 + quad * 8);
#pragma unroll
        for (int i = 0; i < 4; ++i)
#pragma unroll
            for (int j = 0; j < 4; ++j)
                acc[i][j] = __builtin_amdgcn_mfma_f32_16x16x32_bf16(a[i], b[j], acc[i][j], 0, 0, 0);
    }

#pragma unroll
    for (int i = 0; i < 4; ++i)
#pragma unroll
        for (int j = 0; j < 4; ++j)
#pragma unroll
            for (int r = 0; r < 4; ++r) {
                int m = bm * 128 + wr + i * 16 + quad * 4 + r;
                int n = bn * 128 + wc + j * 16 + lrow;
                C[(size_t)m * N + n] = acc[i][j][r];
            }
}

// ---------------------------------------------------------------------------
// Flash attention v6 — round-8 structure reverted (64-key tiles, 2 barriers/
// iter, 16 iters: measured 88 us vs r9's 32-key 93 us regression), with the
// Pl row stride reduced 80 -> 72: stride-80 rows start at word 8*(quad*4+r)
// mod 32 -> 4 rows collide per bank region (8-way on every P write); stride
// 72 -> 4-way (and keeps 16B row alignment for the ds_read_b128 P-frag).
// Band/const split (64-key bounds) + fixed-max softmax unchanged.
// LDS: Ks 8K + Vs 8K + Qpos_l 35K + Pl 9K = 60.7 KB -> 2 blocks/CU.
// Qpos_l row width MUST be >= 272 (prologue writes cols up to 271).
// ---------------------------------------------------------------------------
__global__ __launch_bounds__(256) void flash_attn(
    const uint16_t* __restrict__ Qh, const uint16_t* __restrict__ Kh,
    const uint16_t* __restrict__ Vt, const uint16_t* __restrict__ pos,
    const int* __restrict__ mask, uint16_t* __restrict__ comb)
{
    const int blk = blockIdx.x;     // 0..1023
    const int bh = blk >> 4;        // b*16+h
    const int qt = blk & 15;
    const int b = bh >> 4;
    const int h = bh & 15;
    const int t = threadIdx.x;
    const int lane = t & 63;
    const int wave = t >> 6;
    const int lrow = lane & 15;
    const int quad = lane >> 4;
    const int qb = qt * 64 + wave * 16;

    __shared__ alignas(16) uint16_t Ks[2 * 64 * 32];   // 8 KB
    __shared__ alignas(16) uint16_t Vs[2 * 64 * 32];   // 8 KB
    __shared__ alignas(16) uint16_t Qpos_l[64][274];   // 35072 B
    __shared__ alignas(16) uint16_t Pl[4][16][72];     // 9216 B

    const uint16_t* Qp = Qh + ((size_t)bh * 1024 + qb) * 64;
    short8 aq0 = *(const short8*)(Qp + (size_t)lrow * 64 + quad * 8);
    short8 aq1 = *(const short8*)(Qp + (size_t)lrow * 64 + 32 + quad * 8);

    const f32x4 fz = {0.f, 0.f, 0.f, 0.f};

    // ---- prologue: 16x272 pos-logit slab, B-frags from global (L2-hot) ----
#pragma unroll 4
    for (int nt = 0; nt < 17; ++nt) {
        short8 pb0 = *(const short8*)(pos + (size_t)(nt * 16 + lrow) * 64 + quad * 8);
        short8 pb1 = *(const short8*)(pos + (size_t)(nt * 16 + lrow) * 64 + 32 + quad * 8);
        f32x4 c = __builtin_amdgcn_mfma_f32_16x16x32_bf16(aq0, pb0, fz, 0, 0, 0);
        c = __builtin_amdgcn_mfma_f32_16x16x32_bf16(aq1, pb1, c, 0, 0, 0);
#pragma unroll
        for (int r = 0; r < 4; ++r)
            Qpos_l[wave * 16 + quad * 4 + r][nt * 16 + lrow] = f2bf(c[r]);
    }

    float pcl[4], pch[4];
#pragma unroll
    for (int r = 0; r < 4; ++r) {
        int ql = wave * 16 + quad * 4 + r;
        pcl[r] = bf2f(Qpos_l[ql][0])   * 0.125f;
        pch[r] = bf2f(Qpos_l[ql][256]) * 0.125f;
    }

    const uint16_t* Kp = Kh + (size_t)bh * 65536;
    const uint16_t* Vp = Vt + (size_t)bh * 65536;
    const int* mk = mask + b * 1024;

    const int sg_r = lane >> 2;
    const int sg_c = (lane & 3) * 8;
    const int hw = wave >> 1;
    const int gw = (wave & 1) * 2;

    f32x4 o[4] = {fz, fz, fz, fz};
    float lsum[4] = {0.f, 0.f, 0.f, 0.f};

    for (int kb = 0; kb < 1024; kb += 64) {
        __syncthreads();
#pragma unroll
        for (int gg = 0; gg < 2; ++gg) {
            int g = gw + gg;
            GLDS(Kp + (size_t)(kb + g * 16 + sg_r) * 64 + hw * 32 + sg_c,
                 Ks + hw * 2048 + g * 512);
            GLDS(Vp + (size_t)(g * 16 + sg_r) * 1024 + kb + hw * 32 + sg_c,
                 Vs + hw * 2048 + g * 512);
        }
        __syncthreads();

        f32x4 s[4];
#pragma unroll
        for (int j = 0; j < 4; ++j) {
            short8 k0 = *(const short8*)(Ks + (j * 16 + lrow) * 32 + quad * 8);
            short8 k1 = *(const short8*)(Ks + 2048 + (j * 16 + lrow) * 32 + quad * 8);
            s[j] = __builtin_amdgcn_mfma_f32_16x16x32_bf16(aq0, k0, fz, 0, 0, 0);
            s[j] = __builtin_amdgcn_mfma_f32_16x16x32_bf16(aq1, k1, s[j], 0, 0, 0);
        }

        const int diff = kb - qb;                    // wave-uniform
        if (diff <= -192 || diff >= 144) {
            const bool low = (diff <= -192);
#pragma unroll
            for (int j = 0; j < 4; ++j) {
                const int key = kb + j * 16 + lrow;
                const bool m = (mk[key] != 0);
#pragma unroll
                for (int r = 0; r < 4; ++r) {
                    float pc = low ? pcl[r] : pch[r];
                    float e = m ? 0.f : __expf(__builtin_fmaf(s[j][r], 0.125f, pc));
                    lsum[r] += e;
                    Pl[wave][quad * 4 + r][j * 16 + lrow] = f2bf(e);
                }
            }
        } else {
#pragma unroll
            for (int j = 0; j < 4; ++j) {
                const int key = kb + j * 16 + lrow;
                const bool m = (mk[key] != 0);
#pragma unroll
                for (int r = 0; r < 4; ++r) {
                    int q = qb + quad * 4 + r;
                    int ql = q & 63;
                    int rel = min(max(key - q, -128), 128) + 128;
                    float p = bf2f(Qpos_l[ql][rel]);
                    float e = m ? 0.f : __expf((s[j][r] + p) * 0.125f);
                    lsum[r] += e;
                    Pl[wave][quad * 4 + r][j * 16 + lrow] = f2bf(e);
                }
            }
        }
        short8 ap0 = *(const short8*)(&Pl[wave][lrow][quad * 8]);
        short8 ap1 = *(const short8*)(&Pl[wave][lrow][32 + quad * 8]);

#pragma unroll
        for (int dt = 0; dt < 4; ++dt) {
            short8 v0 = *(const short8*)(Vs + (dt * 16 + lrow) * 32 + quad * 8);
            short8 v1 = *(const short8*)(Vs + 2048 + (dt * 16 + lrow) * 32 + quad * 8);
            o[dt] = __builtin_amdgcn_mfma_f32_16x16x32_bf16(ap0, v0, o[dt], 0, 0, 0);
            o[dt] = __builtin_amdgcn_mfma_f32_16x16x32_bf16(ap1, v1, o[dt], 0, 0, 0);
        }
    }

#pragma unroll
    for (int off = 1; off < 16; off <<= 1)
#pragma unroll
        for (int r = 0; r < 4; ++r)
            lsum[r] += __shfl_xor(lsum[r], off);

    float inv[4];
#pragma unroll
    for (int r = 0; r < 4; ++r) inv[r] = 1.0f / lsum[r];

#pragma unroll
    for (int dt = 0; dt < 4; ++dt)
#pragma unroll
        for (int r = 0; r < 4; ++r) {
            size_t row = (size_t)b * 1024 + qb + quad * 4 + r;
            size_t col = (size_t)h * 64 + dt * 16 + lrow;
            comb[row * 1024 + col] = f2bf(o[dt][r] * inv[r]);
        }
}

// ---------------------------------------------------------------------------
// ws layout (single path, ~40.2 MB — proven safe in all passing rounds):
// Qh 8 | Khd 8 | Vt 8 | comb 8 | W*4 8 | posb | canon
// ---------------------------------------------------------------------------
extern "C" void kernel_launch(void* const* d_in, const int* in_sizes, int n_in,
                              void* d_out, int out_size, void* d_ws, size_t ws_size,
                              hipStream_t stream)
{
    const float* x_q = (const float*)d_in[0];
    const float* x_k = (const float*)d_in[1];
    const float* x_v = (const float*)d_in[2];
    const void*  msk = d_in[3];
    const float* Wq  = (const float*)d_in[4];
    const float* Wk  = (const float*)d_in[5];
    const float* Wv  = (const float*)d_in[6];
    const float* Wo  = (const float*)d_in[7];
    const float* pos = (const float*)d_in[8];

    char* ws = (char*)d_ws;
    const size_t MB = 1u << 20;
    uint16_t* Qh   = (uint16_t*)(ws);
    uint16_t* Khd  = (uint16_t*)(ws + 8 * MB);
    uint16_t* Vt   = (uint16_t*)(ws + 16 * MB);
    uint16_t* comb = (uint16_t*)(ws + 24 * MB);
    uint16_t* Wqb  = (uint16_t*)(ws + 32 * MB);
    uint16_t* Wkb  = (uint16_t*)(ws + 34 * MB);
    uint16_t* Wvb  = (uint16_t*)(ws + 36 * MB);
    uint16_t* Wob  = (uint16_t*)(ws + 38 * MB);
    uint16_t* posb = (uint16_t*)(ws + 40 * MB);      // 272x64 bf16, rows 257+ zero
    int*      canon = (int*)(ws + 40 * MB + 65536);

    CvtArgs ca{};
    int ns = 0;
    ca.seg[ns++] = {Wq, Wqb, 131072};
    ca.seg[ns++] = {Wk, Wkb, 131072};
    ca.seg[ns++] = {Wv, Wvb, 131072};
    ca.seg[ns++] = {Wo, Wob, 131072};
    ca.seg[ns++] = {pos, posb, 2056};              // 257*64/8
    ca.seg[ns++] = {nullptr, posb + 16448, 120};   // zero rows 257..271
    ca.nseg = ns;
    ca.mraw = msk;
    ca.mcanon = canon;
    cvt_bf16<<<dim3(128), dim3(256), 0, stream>>>(ca);

    // Fused Q/K/V projections, fp32-A via glds: 32x8x3 = 768 blocks
    gemm128_qkv<<<dim3(32, 8, 3), dim3(256), 0, stream>>>(
        x_q, x_k, x_v, Wqb, Wkb, Wvb, Qh, Khd, Vt);

    flash_attn<<<dim3(1024), dim3(256), 0, stream>>>(Qh, Khd, Vt, posb, canon, comb);

    // Output projection: comb(bf16) @ Wo_b^T -> fp32 d_out
    gemm128_single<<<dim3(32, 8), dim3(256), 0, stream>>>(
        comb, Wob, (float*)d_out, 4096, 1024, 1024);
}

// Round 11
// 255.663 us; speedup vs baseline: 1.1947x; 1.1947x over previous
//
#include <hip/hip_runtime.h>
#include <hip/hip_bf16.h>
#include <stdint.h>

typedef __attribute__((ext_vector_type(8))) short short8;  // 8 bf16 (4 VGPRs)
typedef __attribute__((ext_vector_type(4))) float f32x4;   // 4 fp32 acc

__device__ __forceinline__ uint16_t f2bf(float f) {
    union { float f; uint32_t u; } v; v.f = f;
    uint32_t r = v.u + 0x7FFF + ((v.u >> 16) & 1);  // RNE
    return (uint16_t)(r >> 16);
}
__device__ __forceinline__ float bf2f(uint16_t u) {
    union { uint32_t u; float f; } v; v.u = ((uint32_t)u) << 16;
    return v.f;
}

template<int F32>
__device__ __forceinline__ uint4 load8(const void* p, size_t off) {
    if (F32) {
        const float* f = (const float*)p + off;
        float4 f0 = *(const float4*)f;
        float4 f1 = *(const float4*)(f + 4);
        uint4 r;
        r.x = (uint32_t)f2bf(f0.x) | ((uint32_t)f2bf(f0.y) << 16);
        r.y = (uint32_t)f2bf(f0.z) | ((uint32_t)f2bf(f0.w) << 16);
        r.z = (uint32_t)f2bf(f1.x) | ((uint32_t)f2bf(f1.y) << 16);
        r.w = (uint32_t)f2bf(f1.z) | ((uint32_t)f2bf(f1.w) << 16);
        return r;
    } else {
        return *(const uint4*)((const uint16_t*)p + off);
    }
}

// global -> LDS direct DMA, 16 B/lane; LDS dest = wave-uniform base + lane*16.
#define GLDS(gp, lp) __builtin_amdgcn_global_load_lds( \
    (const __attribute__((address_space(1))) void*)(gp), \
    (__attribute__((address_space(3))) void*)(lp), 16, 0, 0)

// ---------------------------------------------------------------------------
// cvt (x + weights + pos) + mask canonicalization fused. Block 0 also
// canonicalizes the bool mask (encoding auto-detected).
// ---------------------------------------------------------------------------
struct CvtSeg { const float* s; uint16_t* d; int n8; };
struct CvtArgs { CvtSeg seg[9]; int nseg; const void* mraw; int* mcanon; };

__global__ __launch_bounds__(256) void cvt_bf16(CvtArgs a)
{
    if (blockIdx.x == 0) {
        __shared__ int flags[3];
        const uint32_t* w = (const uint32_t*)a.mraw;
        const uint8_t* b8 = (const uint8_t*)a.mraw;
        const int t = threadIdx.x;
        if (t < 3) flags[t] = 0;
        __syncthreads();
        int fbyte = 0, ff32 = 0, fodd = 0;
        for (int i = t; i < 1024; i += 256) {
            uint32_t v = w[i];
            if (v != 0u && v != 1u && v != 0x3F800000u) fbyte = 1;
            if (v == 0x3F800000u) ff32 = 1;
            if ((i & 1) && v != 0u) fodd = 1;
        }
        if (fbyte) atomicOr(&flags[0], 1);
        if (ff32)  atomicOr(&flags[1], 1);
        if (fodd)  atomicOr(&flags[2], 1);
        __syncthreads();
        int mode;  // 0 = word, 1 = byte, 2 = int64
        if (flags[0]) mode = 1;
        else if (flags[1]) mode = 0;
        else if (!flags[2]) mode = 2;
        else mode = 0;
        for (int k = t; k < 4096; k += 256) {
            int val;
            if (mode == 1)      val = (b8[k] != 0);
            else if (mode == 2) val = (w[2 * k] != 0u);
            else                val = (w[k] != 0u);
            a.mcanon[k] = val;
        }
    }
    const int tid = blockIdx.x * 256 + threadIdx.x;
    const int stride = gridDim.x * 256;
    for (int s = 0; s < a.nseg; ++s) {
        const float* src = a.seg[s].s;
        uint16_t* dst = a.seg[s].d;
        const int n8 = a.seg[s].n8;
        if (src) {
            for (int i = tid; i < n8; i += stride)
                *(uint4*)(dst + (size_t)i * 8) = load8<1>(src, (size_t)i * 8);
        } else {
            const uint4 z = {0u, 0u, 0u, 0u};
            for (int i = tid; i < n8; i += stride)
                *(uint4*)(dst + (size_t)i * 8) = z;
        }
    }
}

// ---------------------------------------------------------------------------
// 128x128-tile NT GEMM body (m97 structure, r8-proven). Pure-bf16 path: both
// operands staged via global_load_lds (64B LDS rows spread fragment reads
// perfectly over 32 banks — the fp32-row variant was 16-way conflicted, r10).
// cm 0: C fp32 row-major; cm 1: bf16 (B,H,T,DH);
// cm 2: bf16 (B,H,DH,T) via per-wave LDS transpose (coalesced 16B stores).
// ---------------------------------------------------------------------------
__device__ __forceinline__ void gemm128_body(
    const uint16_t* __restrict__ A, const uint16_t* __restrict__ B,
    void* __restrict__ C, int M, int N, int K, int cm, int bm, int bn,
    uint16_t* As, uint16_t* Bs)
{
    const int t = threadIdx.x;
    const int lane = t & 63, wave = t >> 6;
    const int lrow = lane & 15, quad = lane >> 4;
    const int wr = (wave >> 1) * 64, wc = (wave & 1) * 64;

    const int g_row = wave * 16 + (lane >> 2);
    const int g_col = (lane & 3) * 8;

    const f32x4 fz = {0.f, 0.f, 0.f, 0.f};
    f32x4 acc[4][4];
#pragma unroll
    for (int i = 0; i < 4; ++i)
#pragma unroll
        for (int j = 0; j < 4; ++j) acc[i][j] = fz;

    for (int k0 = 0; k0 < K; k0 += 32) {
        __syncthreads();
        GLDS(A + (size_t)(bm * 128 + g_row) * K + k0 + g_col,      As + wave * 512);
        GLDS(A + (size_t)(bm * 128 + g_row + 64) * K + k0 + g_col, As + wave * 512 + 2048);
        GLDS(B + (size_t)(bn * 128 + g_row) * K + k0 + g_col,      Bs + wave * 512);
        GLDS(B + (size_t)(bn * 128 + g_row + 64) * K + k0 + g_col, Bs + wave * 512 + 2048);
        __syncthreads();

        short8 a[4], b[4];
#pragma unroll
        for (int i = 0; i < 4; ++i)
            a[i] = *(const short8*)(As + (wr + i * 16 + lrow) * 32 + quad * 8);
#pragma unroll
        for (int j = 0; j < 4; ++j)
            b[j] = *(const short8*)(Bs + (wc + j * 16 + lrow) * 32 + quad * 8);
#pragma unroll
        for (int i = 0; i < 4; ++i)
#pragma unroll
            for (int j = 0; j < 4; ++j)
                acc[i][j] = __builtin_amdgcn_mfma_f32_16x16x32_bf16(a[i], b[j], acc[i][j], 0, 0, 0);
    }

    if (cm == 2) {
        __syncthreads();
        uint16_t* scr = As + wave * 1024;
#pragma unroll
        for (int i = 0; i < 4; ++i)
#pragma unroll
            for (int j = 0; j < 4; ++j) {
                uint2 pk;
                pk.x = (uint32_t)f2bf(acc[i][j][0]) | ((uint32_t)f2bf(acc[i][j][1]) << 16);
                pk.y = (uint32_t)f2bf(acc[i][j][2]) | ((uint32_t)f2bf(acc[i][j][3]) << 16);
                *(uint2*)(scr + lrow * 16 + quad * 4) = pk;
                if (lane < 32) {
                    int n = lane >> 1, m8 = (lane & 1) * 8;
                    short8 vv = *(const short8*)(scr + n * 16 + m8);
                    int ng = bn * 128 + wc + j * 16 + n;        // (h,d)
                    int hh = ng >> 6, d = ng & 63;
                    int mg = bm * 128 + wr + i * 16;            // t base
                    int bb = mg >> 10, tl = (mg & 1023) + m8;
                    *(short8*)((uint16_t*)C +
                        ((((size_t)bb * 16 + hh) * 64 + d) * 1024 + tl)) = vv;
                }
            }
        return;
    }

#pragma unroll
    for (int i = 0; i < 4; ++i)
#pragma unroll
        for (int j = 0; j < 4; ++j)
#pragma unroll
            for (int r = 0; r < 4; ++r) {
                // verified C/D map: row = quad*4 + reg, col = lane&15
                int m = bm * 128 + wr + i * 16 + quad * 4 + r;
                int n = bn * 128 + wc + j * 16 + lrow;
                float val = acc[i][j][r];
                if (cm == 0) {
                    ((float*)C)[(size_t)m * N + n] = val;
                } else {  // cm == 1
                    int bb = m >> 10, tt = m & 1023, hh = n >> 6, d = n & 63;
                    ((uint16_t*)C)[(((size_t)bb * 16 + hh) * 1024 + tt) * 64 + d] = f2bf(val);
                }
            }
}

__global__ __launch_bounds__(256) void gemm128_qkv(
    const uint16_t* __restrict__ xq, const uint16_t* __restrict__ xk, const uint16_t* __restrict__ xv,
    const uint16_t* __restrict__ Wq, const uint16_t* __restrict__ Wk, const uint16_t* __restrict__ Wv,
    uint16_t* __restrict__ Qh, uint16_t* __restrict__ Khd, uint16_t* __restrict__ Vt)
{
    __shared__ alignas(16) uint16_t As[128 * 32];
    __shared__ alignas(16) uint16_t Bs[128 * 32];
    const int z = blockIdx.z;
    const uint16_t* A = (z == 0) ? xq : (z == 1) ? xk : xv;
    const uint16_t* B = (z == 0) ? Wq : (z == 1) ? Wk : Wv;
    void* C = (z == 0) ? (void*)Qh : (z == 1) ? (void*)Khd : (void*)Vt;
    const int cm = (z == 2) ? 2 : 1;
    gemm128_body(A, B, C, 4096, 1024, 1024, cm, blockIdx.x, blockIdx.y, As, Bs);
}

__global__ __launch_bounds__(256) void gemm128_single(
    const uint16_t* __restrict__ A, const uint16_t* __restrict__ B, void* __restrict__ C,
    int M, int N, int K)
{
    __shared__ alignas(16) uint16_t As[128 * 32];
    __shared__ alignas(16) uint16_t Bs[128 * 32];
    gemm128_body(A, B, C, M, N, K, 0, blockIdx.x, blockIdx.y, As, Bs);
}

// ---------------------------------------------------------------------------
// Flash attention — r8-proven structure (64-key tiles, 2 barriers/iter, 16
// iters; measured 88us) with ONE change: Pl row stride 80 -> 72. Stride-80
// put all 4 quads' P-writes in the same 8-word bank window (8-way conflict,
// 16 stores/iter); stride-72 gives word base 16*quad+4r -> quads split over
// two windows (4-way), rows stay 16B-aligned (144B) for the b128 P-frag read.
// Band/const split + fixed-max softmax unchanged (r8-verified).
// LDS: Ks 8K + Vs 8K + Qpos_l 35K + Pl 9K = 60.7 KB -> 2 blocks/CU.
// Qpos_l row width MUST be >= 272 (prologue writes cols up to 271).
// ---------------------------------------------------------------------------
__global__ __launch_bounds__(256) void flash_attn(
    const uint16_t* __restrict__ Qh, const uint16_t* __restrict__ Kh,
    const uint16_t* __restrict__ Vt, const uint16_t* __restrict__ pos,
    const int* __restrict__ mask, uint16_t* __restrict__ comb)
{
    const int blk = blockIdx.x;     // 0..1023
    const int bh = blk >> 4;        // b*16+h
    const int qt = blk & 15;
    const int b = bh >> 4;
    const int h = bh & 15;
    const int t = threadIdx.x;
    const int lane = t & 63;
    const int wave = t >> 6;
    const int lrow = lane & 15;
    const int quad = lane >> 4;
    const int qb = qt * 64 + wave * 16;

    __shared__ alignas(16) uint16_t Ks[2 * 64 * 32];   // 8 KB
    __shared__ alignas(16) uint16_t Vs[2 * 64 * 32];   // 8 KB
    __shared__ alignas(16) uint16_t Qpos_l[64][274];   // 35072 B
    __shared__ alignas(16) uint16_t Pl[4][16][72];     // 9216 B

    const uint16_t* Qp = Qh + ((size_t)bh * 1024 + qb) * 64;
    short8 aq0 = *(const short8*)(Qp + (size_t)lrow * 64 + quad * 8);
    short8 aq1 = *(const short8*)(Qp + (size_t)lrow * 64 + 32 + quad * 8);

    const f32x4 fz = {0.f, 0.f, 0.f, 0.f};

    // ---- prologue: 16x272 pos-logit slab, B-frags from global (L2-hot) ----
#pragma unroll 4
    for (int nt = 0; nt < 17; ++nt) {
        short8 pb0 = *(const short8*)(pos + (size_t)(nt * 16 + lrow) * 64 + quad * 8);
        short8 pb1 = *(const short8*)(pos + (size_t)(nt * 16 + lrow) * 64 + 32 + quad * 8);
        f32x4 c = __builtin_amdgcn_mfma_f32_16x16x32_bf16(aq0, pb0, fz, 0, 0, 0);
        c = __builtin_amdgcn_mfma_f32_16x16x32_bf16(aq1, pb1, c, 0, 0, 0);
#pragma unroll
        for (int r = 0; r < 4; ++r)
            Qpos_l[wave * 16 + quad * 4 + r][nt * 16 + lrow] = f2bf(c[r]);
    }

    float pcl[4], pch[4];
#pragma unroll
    for (int r = 0; r < 4; ++r) {
        int ql = wave * 16 + quad * 4 + r;
        pcl[r] = bf2f(Qpos_l[ql][0])   * 0.125f;
        pch[r] = bf2f(Qpos_l[ql][256]) * 0.125f;
    }

    const uint16_t* Kp = Kh + (size_t)bh * 65536;
    const uint16_t* Vp = Vt + (size_t)bh * 65536;
    const int* mk = mask + b * 1024;

    const int sg_r = lane >> 2;
    const int sg_c = (lane & 3) * 8;
    const int hw = wave >> 1;
    const int gw = (wave & 1) * 2;

    f32x4 o[4] = {fz, fz, fz, fz};
    float lsum[4] = {0.f, 0.f, 0.f, 0.f};

    for (int kb = 0; kb < 1024; kb += 64) {
        __syncthreads();
#pragma unroll
        for (int gg = 0; gg < 2; ++gg) {
            int g = gw + gg;
            GLDS(Kp + (size_t)(kb + g * 16 + sg_r) * 64 + hw * 32 + sg_c,
                 Ks + hw * 2048 + g * 512);
            GLDS(Vp + (size_t)(g * 16 + sg_r) * 1024 + kb + hw * 32 + sg_c,
                 Vs + hw * 2048 + g * 512);
        }
        __syncthreads();

        f32x4 s[4];
#pragma unroll
        for (int j = 0; j < 4; ++j) {
            short8 k0 = *(const short8*)(Ks + (j * 16 + lrow) * 32 + quad * 8);
            short8 k1 = *(const short8*)(Ks + 2048 + (j * 16 + lrow) * 32 + quad * 8);
            s[j] = __builtin_amdgcn_mfma_f32_16x16x32_bf16(aq0, k0, fz, 0, 0, 0);
            s[j] = __builtin_amdgcn_mfma_f32_16x16x32_bf16(aq1, k1, s[j], 0, 0, 0);
        }

        const int diff = kb - qb;                    // wave-uniform
        if (diff <= -192 || diff >= 144) {
            const bool low = (diff <= -192);
#pragma unroll
            for (int j = 0; j < 4; ++j) {
                const int key = kb + j * 16 + lrow;
                const bool m = (mk[key] != 0);
#pragma unroll
                for (int r = 0; r < 4; ++r) {
                    float pc = low ? pcl[r] : pch[r];
                    float e = m ? 0.f : __expf(__builtin_fmaf(s[j][r], 0.125f, pc));
                    lsum[r] += e;
                    Pl[wave][quad * 4 + r][j * 16 + lrow] = f2bf(e);
                }
            }
        } else {
#pragma unroll
            for (int j = 0; j < 4; ++j) {
                const int key = kb + j * 16 + lrow;
                const bool m = (mk[key] != 0);
#pragma unroll
                for (int r = 0; r < 4; ++r) {
                    int q = qb + quad * 4 + r;
                    int ql = q & 63;
                    int rel = min(max(key - q, -128), 128) + 128;
                    float p = bf2f(Qpos_l[ql][rel]);
                    float e = m ? 0.f : __expf((s[j][r] + p) * 0.125f);
                    lsum[r] += e;
                    Pl[wave][quad * 4 + r][j * 16 + lrow] = f2bf(e);
                }
            }
        }
        short8 ap0 = *(const short8*)(&Pl[wave][lrow][quad * 8]);
        short8 ap1 = *(const short8*)(&Pl[wave][lrow][32 + quad * 8]);

#pragma unroll
        for (int dt = 0; dt < 4; ++dt) {
            short8 v0 = *(const short8*)(Vs + (dt * 16 + lrow) * 32 + quad * 8);
            short8 v1 = *(const short8*)(Vs + 2048 + (dt * 16 + lrow) * 32 + quad * 8);
            o[dt] = __builtin_amdgcn_mfma_f32_16x16x32_bf16(ap0, v0, o[dt], 0, 0, 0);
            o[dt] = __builtin_amdgcn_mfma_f32_16x16x32_bf16(ap1, v1, o[dt], 0, 0, 0);
        }
    }

#pragma unroll
    for (int off = 1; off < 16; off <<= 1)
#pragma unroll
        for (int r = 0; r < 4; ++r)
            lsum[r] += __shfl_xor(lsum[r], off);

    float inv[4];
#pragma unroll
    for (int r = 0; r < 4; ++r) inv[r] = 1.0f / lsum[r];

#pragma unroll
    for (int dt = 0; dt < 4; ++dt)
#pragma unroll
        for (int r = 0; r < 4; ++r) {
            size_t row = (size_t)b * 1024 + qb + quad * 4 + r;
            size_t col = (size_t)h * 64 + dt * 16 + lrow;
            comb[row * 1024 + col] = f2bf(o[dt][r] * inv[r]);
        }
}

// ---------------------------------------------------------------------------
// ws layout (hard-coded "big" path, ~56.1 MB; ws_size >= ~72 MB evidenced by
// rounds 0-3 which used 72+ MB layouts without fault):
// Qh 8 | Khd 8 | Vt 8 | xqb 8 (comb reuse) | xkb 8 | xvb 8 | W*4 8 | posb | canon
// ---------------------------------------------------------------------------
extern "C" void kernel_launch(void* const* d_in, const int* in_sizes, int n_in,
                              void* d_out, int out_size, void* d_ws, size_t ws_size,
                              hipStream_t stream)
{
    const float* x_q = (const float*)d_in[0];
    const float* x_k = (const float*)d_in[1];
    const float* x_v = (const float*)d_in[2];
    const void*  msk = d_in[3];
    const float* Wq  = (const float*)d_in[4];
    const float* Wk  = (const float*)d_in[5];
    const float* Wv  = (const float*)d_in[6];
    const float* Wo  = (const float*)d_in[7];
    const float* pos = (const float*)d_in[8];

    char* ws = (char*)d_ws;
    const size_t MB = 1u << 20;
    uint16_t* Qh   = (uint16_t*)(ws);
    uint16_t* Khd  = (uint16_t*)(ws + 8 * MB);
    uint16_t* Vt   = (uint16_t*)(ws + 16 * MB);
    uint16_t* xqb  = (uint16_t*)(ws + 24 * MB);
    uint16_t* xkb  = (uint16_t*)(ws + 32 * MB);
    uint16_t* xvb  = (uint16_t*)(ws + 40 * MB);
    uint16_t* Wqb  = (uint16_t*)(ws + 48 * MB);
    uint16_t* Wkb  = (uint16_t*)(ws + 50 * MB);
    uint16_t* Wvb  = (uint16_t*)(ws + 52 * MB);
    uint16_t* Wob  = (uint16_t*)(ws + 54 * MB);
    uint16_t* posb = (uint16_t*)(ws + 56 * MB);       // 272x64 bf16, rows 257+ zero
    int*      canon = (int*)(ws + 56 * MB + 65536);
    uint16_t* comb = xqb;  // xqb dead after projections; flash runs after them

    CvtArgs ca{};
    int ns = 0;
    ca.seg[ns++] = {x_q, xqb, 524288};
    ca.seg[ns++] = {x_k, xkb, 524288};
    ca.seg[ns++] = {x_v, xvb, 524288};
    ca.seg[ns++] = {Wq, Wqb, 131072};
    ca.seg[ns++] = {Wk, Wkb, 131072};
    ca.seg[ns++] = {Wv, Wvb, 131072};
    ca.seg[ns++] = {Wo, Wob, 131072};
    ca.seg[ns++] = {pos, posb, 2056};              // 257*64/8
    ca.seg[ns++] = {nullptr, posb + 16448, 120};   // zero rows 257..271
    ca.nseg = ns;
    ca.mraw = msk;
    ca.mcanon = canon;
    cvt_bf16<<<dim3(512), dim3(256), 0, stream>>>(ca);

    // Fused Q/K/V projections, pure-bf16 glds staging: 32x8x3 = 768 blocks
    gemm128_qkv<<<dim3(32, 8, 3), dim3(256), 0, stream>>>(
        xqb, xkb, xvb, Wqb, Wkb, Wvb, Qh, Khd, Vt);

    flash_attn<<<dim3(1024), dim3(256), 0, stream>>>(Qh, Khd, Vt, posb, canon, comb);

    // Output projection: comb(bf16) @ Wo_b^T -> fp32 d_out
    gemm128_single<<<dim3(32, 8), dim3(256), 0, stream>>>(
        comb, Wob, d_out, 4096, 1024, 1024);
}

// Round 12
// 254.646 us; speedup vs baseline: 1.1995x; 1.0040x over previous
//
#include <hip/hip_runtime.h>
#include <hip/hip_bf16.h>
#include <stdint.h>

typedef __attribute__((ext_vector_type(8))) short short8;  // 8 bf16 (4 VGPRs)
typedef __attribute__((ext_vector_type(4))) float f32x4;   // 4 fp32 acc

__device__ __forceinline__ uint16_t f2bf(float f) {
    union { float f; uint32_t u; } v; v.f = f;
    uint32_t r = v.u + 0x7FFF + ((v.u >> 16) & 1);  // RNE
    return (uint16_t)(r >> 16);
}
__device__ __forceinline__ float bf2f(uint16_t u) {
    union { uint32_t u; float f; } v; v.u = ((uint32_t)u) << 16;
    return v.f;
}

template<int F32>
__device__ __forceinline__ uint4 load8(const void* p, size_t off) {
    if (F32) {
        const float* f = (const float*)p + off;
        float4 f0 = *(const float4*)f;
        float4 f1 = *(const float4*)(f + 4);
        uint4 r;
        r.x = (uint32_t)f2bf(f0.x) | ((uint32_t)f2bf(f0.y) << 16);
        r.y = (uint32_t)f2bf(f0.z) | ((uint32_t)f2bf(f0.w) << 16);
        r.z = (uint32_t)f2bf(f1.x) | ((uint32_t)f2bf(f1.y) << 16);
        r.w = (uint32_t)f2bf(f1.z) | ((uint32_t)f2bf(f1.w) << 16);
        return r;
    } else {
        return *(const uint4*)((const uint16_t*)p + off);
    }
}

// global -> LDS direct DMA, 16 B/lane; LDS dest = wave-uniform base + lane*16.
#define GLDS(gp, lp) __builtin_amdgcn_global_load_lds( \
    (const __attribute__((address_space(1))) void*)(gp), \
    (__attribute__((address_space(3))) void*)(lp), 16, 0, 0)

// ---------------------------------------------------------------------------
// cvt (x + weights + pos) + mask canonicalization fused. Block 0 also
// canonicalizes the bool mask (encoding auto-detected).
// ---------------------------------------------------------------------------
struct CvtSeg { const float* s; uint16_t* d; int n8; };
struct CvtArgs { CvtSeg seg[9]; int nseg; const void* mraw; int* mcanon; };

__global__ __launch_bounds__(256) void cvt_bf16(CvtArgs a)
{
    if (blockIdx.x == 0) {
        __shared__ int flags[3];
        const uint32_t* w = (const uint32_t*)a.mraw;
        const uint8_t* b8 = (const uint8_t*)a.mraw;
        const int t = threadIdx.x;
        if (t < 3) flags[t] = 0;
        __syncthreads();
        int fbyte = 0, ff32 = 0, fodd = 0;
        for (int i = t; i < 1024; i += 256) {
            uint32_t v = w[i];
            if (v != 0u && v != 1u && v != 0x3F800000u) fbyte = 1;
            if (v == 0x3F800000u) ff32 = 1;
            if ((i & 1) && v != 0u) fodd = 1;
        }
        if (fbyte) atomicOr(&flags[0], 1);
        if (ff32)  atomicOr(&flags[1], 1);
        if (fodd)  atomicOr(&flags[2], 1);
        __syncthreads();
        int mode;  // 0 = word, 1 = byte, 2 = int64
        if (flags[0]) mode = 1;
        else if (flags[1]) mode = 0;
        else if (!flags[2]) mode = 2;
        else mode = 0;
        for (int k = t; k < 4096; k += 256) {
            int val;
            if (mode == 1)      val = (b8[k] != 0);
            else if (mode == 2) val = (w[2 * k] != 0u);
            else                val = (w[k] != 0u);
            a.mcanon[k] = val;
        }
    }
    const int tid = blockIdx.x * 256 + threadIdx.x;
    const int stride = gridDim.x * 256;
    for (int s = 0; s < a.nseg; ++s) {
        const float* src = a.seg[s].s;
        uint16_t* dst = a.seg[s].d;
        const int n8 = a.seg[s].n8;
        if (src) {
            for (int i = tid; i < n8; i += stride)
                *(uint4*)(dst + (size_t)i * 8) = load8<1>(src, (size_t)i * 8);
        } else {
            const uint4 z = {0u, 0u, 0u, 0u};
            for (int i = tid; i < n8; i += stride)
                *(uint4*)(dst + (size_t)i * 8) = z;
        }
    }
}

// ---------------------------------------------------------------------------
// 128x128-tile NT GEMM (m97 structure, r8/r11-proven) — QKV projections.
// Pure-bf16 glds staging (64B LDS rows = conflict-free fragment reads).
// cm 1: bf16 (B,H,T,DH); cm 2: bf16 (B,H,DH,T) via per-wave LDS transpose.
// ---------------------------------------------------------------------------
__global__ __launch_bounds__(256) void gemm128_qkv(
    const uint16_t* __restrict__ xq, const uint16_t* __restrict__ xk, const uint16_t* __restrict__ xv,
    const uint16_t* __restrict__ Wq, const uint16_t* __restrict__ Wk, const uint16_t* __restrict__ Wv,
    uint16_t* __restrict__ Qh, uint16_t* __restrict__ Khd, uint16_t* __restrict__ Vt)
{
    __shared__ alignas(16) uint16_t As[128 * 32];
    __shared__ alignas(16) uint16_t Bs[128 * 32];

    const int z = blockIdx.z;
    const uint16_t* A = (z == 0) ? xq : (z == 1) ? xk : xv;
    const uint16_t* B = (z == 0) ? Wq : (z == 1) ? Wk : Wv;
    uint16_t* C = (z == 0) ? Qh : (z == 1) ? Khd : Vt;
    const int cm = (z == 2) ? 2 : 1;
    const int bm = blockIdx.x, bn = blockIdx.y;
    const int K = 1024;

    const int t = threadIdx.x;
    const int lane = t & 63, wave = t >> 6;
    const int lrow = lane & 15, quad = lane >> 4;
    const int wr = (wave >> 1) * 64, wc = (wave & 1) * 64;
    const int g_row = wave * 16 + (lane >> 2);
    const int g_col = (lane & 3) * 8;

    const f32x4 fz = {0.f, 0.f, 0.f, 0.f};
    f32x4 acc[4][4];
#pragma unroll
    for (int i = 0; i < 4; ++i)
#pragma unroll
        for (int j = 0; j < 4; ++j) acc[i][j] = fz;

    for (int k0 = 0; k0 < K; k0 += 32) {
        __syncthreads();
        GLDS(A + (size_t)(bm * 128 + g_row) * K + k0 + g_col,      As + wave * 512);
        GLDS(A + (size_t)(bm * 128 + g_row + 64) * K + k0 + g_col, As + wave * 512 + 2048);
        GLDS(B + (size_t)(bn * 128 + g_row) * K + k0 + g_col,      Bs + wave * 512);
        GLDS(B + (size_t)(bn * 128 + g_row + 64) * K + k0 + g_col, Bs + wave * 512 + 2048);
        __syncthreads();

        short8 a[4], b[4];
#pragma unroll
        for (int i = 0; i < 4; ++i)
            a[i] = *(const short8*)(As + (wr + i * 16 + lrow) * 32 + quad * 8);
#pragma unroll
        for (int j = 0; j < 4; ++j)
            b[j] = *(const short8*)(Bs + (wc + j * 16 + lrow) * 32 + quad * 8);
#pragma unroll
        for (int i = 0; i < 4; ++i)
#pragma unroll
            for (int j = 0; j < 4; ++j)
                acc[i][j] = __builtin_amdgcn_mfma_f32_16x16x32_bf16(a[i], b[j], acc[i][j], 0, 0, 0);
    }

    if (cm == 2) {
        __syncthreads();
        uint16_t* scr = As + wave * 1024;
#pragma unroll
        for (int i = 0; i < 4; ++i)
#pragma unroll
            for (int j = 0; j < 4; ++j) {
                uint2 pk;
                pk.x = (uint32_t)f2bf(acc[i][j][0]) | ((uint32_t)f2bf(acc[i][j][1]) << 16);
                pk.y = (uint32_t)f2bf(acc[i][j][2]) | ((uint32_t)f2bf(acc[i][j][3]) << 16);
                *(uint2*)(scr + lrow * 16 + quad * 4) = pk;
                if (lane < 32) {
                    int n = lane >> 1, m8 = (lane & 1) * 8;
                    short8 vv = *(const short8*)(scr + n * 16 + m8);
                    int ng = bn * 128 + wc + j * 16 + n;        // (h,d)
                    int hh = ng >> 6, d = ng & 63;
                    int mg = bm * 128 + wr + i * 16;            // t base
                    int bb = mg >> 10, tl = (mg & 1023) + m8;
                    *(short8*)(C + ((((size_t)bb * 16 + hh) * 64 + d) * 1024 + tl)) = vv;
                }
            }
        return;
    }

#pragma unroll
    for (int i = 0; i < 4; ++i)
#pragma unroll
        for (int j = 0; j < 4; ++j)
#pragma unroll
            for (int r = 0; r < 4; ++r) {
                // verified C/D map: row = quad*4 + reg, col = lane&15
                int m = bm * 128 + wr + i * 16 + quad * 4 + r;
                int n = bn * 128 + wc + j * 16 + lrow;
                int bb = m >> 10, tt = m & 1023, hh = n >> 6, d = n & 63;
                C[(((size_t)bb * 16 + hh) * 1024 + tt) * 64 + d] = f2bf(acc[i][j][r]);
            }
}

// ---------------------------------------------------------------------------
// Output projection, 64x128 tiles -> 512 blocks (2/CU; the old 128x128 grid
// was 256 blocks = 1 block/CU = 4 waves/CU, nothing to hide barrier drains).
// Waves 2x2 of 32x64 (8 MFMA/iter). A 4KB + B 8KB LDS.
// ---------------------------------------------------------------------------
__global__ __launch_bounds__(256) void gemm_out(
    const uint16_t* __restrict__ A, const uint16_t* __restrict__ B,
    float* __restrict__ C, int M, int N, int K)
{
    __shared__ alignas(16) uint16_t As[64 * 32];
    __shared__ alignas(16) uint16_t Bs[128 * 32];

    const int t = threadIdx.x;
    const int lane = t & 63, wave = t >> 6;
    const int lrow = lane & 15, quad = lane >> 4;
    const int wr = (wave >> 1) * 32, wc = (wave & 1) * 64;
    const int g_row = wave * 16 + (lane >> 2);
    const int g_col = (lane & 3) * 8;
    const int bm = blockIdx.x, bn = blockIdx.y;

    const f32x4 fz = {0.f, 0.f, 0.f, 0.f};
    f32x4 acc[2][4];
#pragma unroll
    for (int i = 0; i < 2; ++i)
#pragma unroll
        for (int j = 0; j < 4; ++j) acc[i][j] = fz;

    for (int k0 = 0; k0 < K; k0 += 32) {
        __syncthreads();
        GLDS(A + (size_t)(bm * 64 + g_row) * K + k0 + g_col,       As + wave * 512);
        GLDS(B + (size_t)(bn * 128 + g_row) * K + k0 + g_col,      Bs + wave * 512);
        GLDS(B + (size_t)(bn * 128 + g_row + 64) * K + k0 + g_col, Bs + wave * 512 + 2048);
        __syncthreads();

        short8 a[2], b[4];
#pragma unroll
        for (int i = 0; i < 2; ++i)
            a[i] = *(const short8*)(As + (wr + i * 16 + lrow) * 32 + quad * 8);
#pragma unroll
        for (int j = 0; j < 4; ++j)
            b[j] = *(const short8*)(Bs + (wc + j * 16 + lrow) * 32 + quad * 8);
#pragma unroll
        for (int i = 0; i < 2; ++i)
#pragma unroll
            for (int j = 0; j < 4; ++j)
                acc[i][j] = __builtin_amdgcn_mfma_f32_16x16x32_bf16(a[i], b[j], acc[i][j], 0, 0, 0);
    }

#pragma unroll
    for (int i = 0; i < 2; ++i)
#pragma unroll
        for (int j = 0; j < 4; ++j)
#pragma unroll
            for (int r = 0; r < 4; ++r) {
                int m = bm * 64 + wr + i * 16 + quad * 4 + r;
                int n = bn * 128 + wc + j * 16 + lrow;
                C[(size_t)m * N + n] = acc[i][j][r];
            }
}

// ---------------------------------------------------------------------------
// Flash attention v7 — double-buffered K/V staging.
// r8-r11 evidence: the 2-barrier loop exposed the full K/V load latency at
// every iteration (glds issued immediately before the draining barrier) with
// only 2 blocks/CU to hide it. Now: tile k+1 is staged right AFTER the single
// per-iter barrier into the other buffer, so the prefetch has the whole
// compute phase to land; barriers drop 32 -> 16 per pass. Tile-0 glds issues
// before the pos-slab prologue (its latency hides under 17 MFMAs).
// Pl stride 72 (4-way, r11-verified), band/const split, fixed-max softmax.
// LDS: Ks 16K + Vs 16K + Qpos_l 35K + Pl 9K = 77 KB -> 2 blocks/CU.
// Qpos_l row width MUST be >= 272 (prologue writes cols up to 271).
// ---------------------------------------------------------------------------
__global__ __launch_bounds__(256) void flash_attn(
    const uint16_t* __restrict__ Qh, const uint16_t* __restrict__ Kh,
    const uint16_t* __restrict__ Vt, const uint16_t* __restrict__ pos,
    const int* __restrict__ mask, uint16_t* __restrict__ comb)
{
    const int blk = blockIdx.x;     // 0..1023
    const int bh = blk >> 4;        // b*16+h
    const int qt = blk & 15;
    const int b = bh >> 4;
    const int h = bh & 15;
    const int t = threadIdx.x;
    const int lane = t & 63;
    const int wave = t >> 6;
    const int lrow = lane & 15;
    const int quad = lane >> 4;
    const int qb = qt * 64 + wave * 16;

    __shared__ alignas(16) uint16_t Ks[2][4096];       // 2 x 8 KB
    __shared__ alignas(16) uint16_t Vs[2][4096];       // 2 x 8 KB
    __shared__ alignas(16) uint16_t Qpos_l[64][274];   // 35072 B
    __shared__ alignas(16) uint16_t Pl[4][16][72];     // 9216 B

    const uint16_t* Kp = Kh + (size_t)bh * 65536;
    const uint16_t* Vp = Vt + (size_t)bh * 65536;
    const int* mk = mask + b * 1024;

    const int sg_r = lane >> 2;
    const int sg_c = (lane & 3) * 8;
    const int hw = wave >> 1;
    const int gw = (wave & 1) * 2;

    // issue tile-0 staging first: latency hides under the pos-slab prologue
#pragma unroll
    for (int gg = 0; gg < 2; ++gg) {
        int g = gw + gg;
        GLDS(Kp + (size_t)(g * 16 + sg_r) * 64 + hw * 32 + sg_c, &Ks[0][hw * 2048 + g * 512]);
        GLDS(Vp + (size_t)(g * 16 + sg_r) * 1024 + hw * 32 + sg_c, &Vs[0][hw * 2048 + g * 512]);
    }

    const uint16_t* Qp = Qh + ((size_t)bh * 1024 + qb) * 64;
    short8 aq0 = *(const short8*)(Qp + (size_t)lrow * 64 + quad * 8);
    short8 aq1 = *(const short8*)(Qp + (size_t)lrow * 64 + 32 + quad * 8);

    const f32x4 fz = {0.f, 0.f, 0.f, 0.f};

    // ---- prologue: 16x272 pos-logit slab, B-frags from global (L2-hot) ----
#pragma unroll 4
    for (int nt = 0; nt < 17; ++nt) {
        short8 pb0 = *(const short8*)(pos + (size_t)(nt * 16 + lrow) * 64 + quad * 8);
        short8 pb1 = *(const short8*)(pos + (size_t)(nt * 16 + lrow) * 64 + 32 + quad * 8);
        f32x4 c = __builtin_amdgcn_mfma_f32_16x16x32_bf16(aq0, pb0, fz, 0, 0, 0);
        c = __builtin_amdgcn_mfma_f32_16x16x32_bf16(aq1, pb1, c, 0, 0, 0);
#pragma unroll
        for (int r = 0; r < 4; ++r)
            Qpos_l[wave * 16 + quad * 4 + r][nt * 16 + lrow] = f2bf(c[r]);
    }

    float pcl[4], pch[4];
#pragma unroll
    for (int r = 0; r < 4; ++r) {
        int ql = wave * 16 + quad * 4 + r;
        pcl[r] = bf2f(Qpos_l[ql][0])   * 0.125f;
        pch[r] = bf2f(Qpos_l[ql][256]) * 0.125f;
    }

    f32x4 o[4] = {fz, fz, fz, fz};
    float lsum[4] = {0.f, 0.f, 0.f, 0.f};

    for (int kb = 0; kb < 1024; kb += 64) {
        const int cur = (kb >> 6) & 1;
        __syncthreads();  // drains prefetch (issued last iter); guards buffers
        if (kb + 64 < 1024) {
            const int nxt = cur ^ 1;
#pragma unroll
            for (int gg = 0; gg < 2; ++gg) {
                int g = gw + gg;
                GLDS(Kp + (size_t)(kb + 64 + g * 16 + sg_r) * 64 + hw * 32 + sg_c,
                     &Ks[nxt][hw * 2048 + g * 512]);
                GLDS(Vp + (size_t)(g * 16 + sg_r) * 1024 + kb + 64 + hw * 32 + sg_c,
                     &Vs[nxt][hw * 2048 + g * 512]);
            }
        }
        const uint16_t* Kc = Ks[cur];
        const uint16_t* Vc = Vs[cur];

        f32x4 s[4];
#pragma unroll
        for (int j = 0; j < 4; ++j) {
            short8 k0 = *(const short8*)(Kc + (j * 16 + lrow) * 32 + quad * 8);
            short8 k1 = *(const short8*)(Kc + 2048 + (j * 16 + lrow) * 32 + quad * 8);
            s[j] = __builtin_amdgcn_mfma_f32_16x16x32_bf16(aq0, k0, fz, 0, 0, 0);
            s[j] = __builtin_amdgcn_mfma_f32_16x16x32_bf16(aq1, k1, s[j], 0, 0, 0);
        }

        const int diff = kb - qb;                    // wave-uniform
        if (diff <= -192 || diff >= 144) {
            const bool low = (diff <= -192);
#pragma unroll
            for (int j = 0; j < 4; ++j) {
                const int key = kb + j * 16 + lrow;
                const bool m = (mk[key] != 0);
#pragma unroll
                for (int r = 0; r < 4; ++r) {
                    float pc = low ? pcl[r] : pch[r];
                    float e = m ? 0.f : __expf(__builtin_fmaf(s[j][r], 0.125f, pc));
                    lsum[r] += e;
                    Pl[wave][quad * 4 + r][j * 16 + lrow] = f2bf(e);
                }
            }
        } else {
#pragma unroll
            for (int j = 0; j < 4; ++j) {
                const int key = kb + j * 16 + lrow;
                const bool m = (mk[key] != 0);
#pragma unroll
                for (int r = 0; r < 4; ++r) {
                    int q = qb + quad * 4 + r;
                    int ql = q & 63;
                    int rel = min(max(key - q, -128), 128) + 128;
                    float p = bf2f(Qpos_l[ql][rel]);
                    float e = m ? 0.f : __expf((s[j][r] + p) * 0.125f);
                    lsum[r] += e;
                    Pl[wave][quad * 4 + r][j * 16 + lrow] = f2bf(e);
                }
            }
        }
        short8 ap0 = *(const short8*)(&Pl[wave][lrow][quad * 8]);
        short8 ap1 = *(const short8*)(&Pl[wave][lrow][32 + quad * 8]);

#pragma unroll
        for (int dt = 0; dt < 4; ++dt) {
            short8 v0 = *(const short8*)(Vc + (dt * 16 + lrow) * 32 + quad * 8);
            short8 v1 = *(const short8*)(Vc + 2048 + (dt * 16 + lrow) * 32 + quad * 8);
            o[dt] = __builtin_amdgcn_mfma_f32_16x16x32_bf16(ap0, v0, o[dt], 0, 0, 0);
            o[dt] = __builtin_amdgcn_mfma_f32_16x16x32_bf16(ap1, v1, o[dt], 0, 0, 0);
        }
    }

#pragma unroll
    for (int off = 1; off < 16; off <<= 1)
#pragma unroll
        for (int r = 0; r < 4; ++r)
            lsum[r] += __shfl_xor(lsum[r], off);

    float inv[4];
#pragma unroll
    for (int r = 0; r < 4; ++r) inv[r] = 1.0f / lsum[r];

#pragma unroll
    for (int dt = 0; dt < 4; ++dt)
#pragma unroll
        for (int r = 0; r < 4; ++r) {
            size_t row = (size_t)b * 1024 + qb + quad * 4 + r;
            size_t col = (size_t)h * 64 + dt * 16 + lrow;
            comb[row * 1024 + col] = f2bf(o[dt][r] * inv[r]);
        }
}

// ---------------------------------------------------------------------------
// ws layout (hard-coded "big" path, ~56.1 MB; ws_size >= ~72 MB evidenced by
// rounds 0-3 which used 72+ MB layouts without fault):
// Qh 8 | Khd 8 | Vt 8 | xqb 8 (comb reuse) | xkb 8 | xvb 8 | W*4 8 | posb | canon
// ---------------------------------------------------------------------------
extern "C" void kernel_launch(void* const* d_in, const int* in_sizes, int n_in,
                              void* d_out, int out_size, void* d_ws, size_t ws_size,
                              hipStream_t stream)
{
    const float* x_q = (const float*)d_in[0];
    const float* x_k = (const float*)d_in[1];
    const float* x_v = (const float*)d_in[2];
    const void*  msk = d_in[3];
    const float* Wq  = (const float*)d_in[4];
    const float* Wk  = (const float*)d_in[5];
    const float* Wv  = (const float*)d_in[6];
    const float* Wo  = (const float*)d_in[7];
    const float* pos = (const float*)d_in[8];

    char* ws = (char*)d_ws;
    const size_t MB = 1u << 20;
    uint16_t* Qh   = (uint16_t*)(ws);
    uint16_t* Khd  = (uint16_t*)(ws + 8 * MB);
    uint16_t* Vt   = (uint16_t*)(ws + 16 * MB);
    uint16_t* xqb  = (uint16_t*)(ws + 24 * MB);
    uint16_t* xkb  = (uint16_t*)(ws + 32 * MB);
    uint16_t* xvb  = (uint16_t*)(ws + 40 * MB);
    uint16_t* Wqb  = (uint16_t*)(ws + 48 * MB);
    uint16_t* Wkb  = (uint16_t*)(ws + 50 * MB);
    uint16_t* Wvb  = (uint16_t*)(ws + 52 * MB);
    uint16_t* Wob  = (uint16_t*)(ws + 54 * MB);
    uint16_t* posb = (uint16_t*)(ws + 56 * MB);       // 272x64 bf16, rows 257+ zero
    int*      canon = (int*)(ws + 56 * MB + 65536);
    uint16_t* comb = xqb;  // xqb dead after projections; flash runs after them

    CvtArgs ca{};
    int ns = 0;
    ca.seg[ns++] = {x_q, xqb, 524288};
    ca.seg[ns++] = {x_k, xkb, 524288};
    ca.seg[ns++] = {x_v, xvb, 524288};
    ca.seg[ns++] = {Wq, Wqb, 131072};
    ca.seg[ns++] = {Wk, Wkb, 131072};
    ca.seg[ns++] = {Wv, Wvb, 131072};
    ca.seg[ns++] = {Wo, Wob, 131072};
    ca.seg[ns++] = {pos, posb, 2056};              // 257*64/8
    ca.seg[ns++] = {nullptr, posb + 16448, 120};   // zero rows 257..271
    ca.nseg = ns;
    ca.mraw = msk;
    ca.mcanon = canon;
    cvt_bf16<<<dim3(512), dim3(256), 0, stream>>>(ca);

    // Fused Q/K/V projections, pure-bf16 glds staging: 32x8x3 = 768 blocks
    gemm128_qkv<<<dim3(32, 8, 3), dim3(256), 0, stream>>>(
        xqb, xkb, xvb, Wqb, Wkb, Wvb, Qh, Khd, Vt);

    flash_attn<<<dim3(1024), dim3(256), 0, stream>>>(Qh, Khd, Vt, posb, canon, comb);

    // Output projection: comb(bf16) @ Wo_b^T -> fp32 d_out (64x128 tiles)
    gemm_out<<<dim3(64, 8), dim3(256), 0, stream>>>(
        comb, Wob, (float*)d_out, 4096, 1024, 1024);
}

// Round 13
// 249.172 us; speedup vs baseline: 1.2258x; 1.0220x over previous
//
#include <hip/hip_runtime.h>
#include <hip/hip_bf16.h>
#include <stdint.h>

typedef __attribute__((ext_vector_type(8))) short short8;  // 8 bf16 (4 VGPRs)
typedef __attribute__((ext_vector_type(4))) float f32x4;   // 4 fp32 acc

__device__ __forceinline__ uint16_t f2bf(float f) {
    union { float f; uint32_t u; } v; v.f = f;
    uint32_t r = v.u + 0x7FFF + ((v.u >> 16) & 1);  // RNE
    return (uint16_t)(r >> 16);
}
__device__ __forceinline__ float bf2f(uint16_t u) {
    union { uint32_t u; float f; } v; v.u = ((uint32_t)u) << 16;
    return v.f;
}

template<int F32>
__device__ __forceinline__ uint4 load8(const void* p, size_t off) {
    if (F32) {
        const float* f = (const float*)p + off;
        float4 f0 = *(const float4*)f;
        float4 f1 = *(const float4*)(f + 4);
        uint4 r;
        r.x = (uint32_t)f2bf(f0.x) | ((uint32_t)f2bf(f0.y) << 16);
        r.y = (uint32_t)f2bf(f0.z) | ((uint32_t)f2bf(f0.w) << 16);
        r.z = (uint32_t)f2bf(f1.x) | ((uint32_t)f2bf(f1.y) << 16);
        r.w = (uint32_t)f2bf(f1.z) | ((uint32_t)f2bf(f1.w) << 16);
        return r;
    } else {
        return *(const uint4*)((const uint16_t*)p + off);
    }
}

// global -> LDS direct DMA, 16 B/lane; LDS dest = wave-uniform base + lane*16.
#define GLDS(gp, lp) __builtin_amdgcn_global_load_lds( \
    (const __attribute__((address_space(1))) void*)(gp), \
    (__attribute__((address_space(3))) void*)(lp), 16, 0, 0)

// ---------------------------------------------------------------------------
// cvt (x + weights + pos) + mask canonicalization fused. Block 0 also
// canonicalizes the bool mask (encoding auto-detected).
// ---------------------------------------------------------------------------
struct CvtSeg { const float* s; uint16_t* d; int n8; };
struct CvtArgs { CvtSeg seg[9]; int nseg; const void* mraw; int* mcanon; };

__global__ __launch_bounds__(256) void cvt_bf16(CvtArgs a)
{
    if (blockIdx.x == 0) {
        __shared__ int flags[3];
        const uint32_t* w = (const uint32_t*)a.mraw;
        const uint8_t* b8 = (const uint8_t*)a.mraw;
        const int t = threadIdx.x;
        if (t < 3) flags[t] = 0;
        __syncthreads();
        int fbyte = 0, ff32 = 0, fodd = 0;
        for (int i = t; i < 1024; i += 256) {
            uint32_t v = w[i];
            if (v != 0u && v != 1u && v != 0x3F800000u) fbyte = 1;
            if (v == 0x3F800000u) ff32 = 1;
            if ((i & 1) && v != 0u) fodd = 1;
        }
        if (fbyte) atomicOr(&flags[0], 1);
        if (ff32)  atomicOr(&flags[1], 1);
        if (fodd)  atomicOr(&flags[2], 1);
        __syncthreads();
        int mode;  // 0 = word, 1 = byte, 2 = int64
        if (flags[0]) mode = 1;
        else if (flags[1]) mode = 0;
        else if (!flags[2]) mode = 2;
        else mode = 0;
        for (int k = t; k < 4096; k += 256) {
            int val;
            if (mode == 1)      val = (b8[k] != 0);
            else if (mode == 2) val = (w[2 * k] != 0u);
            else                val = (w[k] != 0u);
            a.mcanon[k] = val;
        }
    }
    const int tid = blockIdx.x * 256 + threadIdx.x;
    const int stride = gridDim.x * 256;
    for (int s = 0; s < a.nseg; ++s) {
        const float* src = a.seg[s].s;
        uint16_t* dst = a.seg[s].d;
        const int n8 = a.seg[s].n8;
        if (src) {
            for (int i = tid; i < n8; i += stride)
                *(uint4*)(dst + (size_t)i * 8) = load8<1>(src, (size_t)i * 8);
        } else {
            const uint4 z = {0u, 0u, 0u, 0u};
            for (int i = tid; i < n8; i += stride)
                *(uint4*)(dst + (size_t)i * 8) = z;
        }
    }
}

// ---------------------------------------------------------------------------
// QKV GEMM, 128x128 tile, BK=64 as TWO 128x32 sub-tiles per operand (keeps
// the conflict-free 64B LDS rows and valid glds lane maps — padding a 128B
// row would either 16-way-conflict (r10) or break glds's contiguous-dest
// rule). Barriers halve: 32 iters x 2 -> 16 x 2; 32 MFMA per barrier-pair.
// LDS 32KB. cm 1: (B,H,T,DH); cm 2: (B,H,DH,T) via per-wave LDS transpose.
// ---------------------------------------------------------------------------
__global__ __launch_bounds__(256) void gemm128_qkv(
    const uint16_t* __restrict__ xq, const uint16_t* __restrict__ xk, const uint16_t* __restrict__ xv,
    const uint16_t* __restrict__ Wq, const uint16_t* __restrict__ Wk, const uint16_t* __restrict__ Wv,
    uint16_t* __restrict__ Qh, uint16_t* __restrict__ Khd, uint16_t* __restrict__ Vt)
{
    __shared__ alignas(16) uint16_t As[2][128 * 32];   // k-halves
    __shared__ alignas(16) uint16_t Bs[2][128 * 32];

    const int z = blockIdx.z;
    const uint16_t* A = (z == 0) ? xq : (z == 1) ? xk : xv;
    const uint16_t* B = (z == 0) ? Wq : (z == 1) ? Wk : Wv;
    uint16_t* C = (z == 0) ? Qh : (z == 1) ? Khd : Vt;
    const int cm = (z == 2) ? 2 : 1;
    const int bm = blockIdx.x, bn = blockIdx.y;
    const int K = 1024;

    const int t = threadIdx.x;
    const int lane = t & 63, wave = t >> 6;
    const int lrow = lane & 15, quad = lane >> 4;
    const int wr = (wave >> 1) * 64, wc = (wave & 1) * 64;
    const int g_row = wave * 16 + (lane >> 2);
    const int g_col = (lane & 3) * 8;

    const f32x4 fz = {0.f, 0.f, 0.f, 0.f};
    f32x4 acc[4][4];
#pragma unroll
    for (int i = 0; i < 4; ++i)
#pragma unroll
        for (int j = 0; j < 4; ++j) acc[i][j] = fz;

    for (int k0 = 0; k0 < K; k0 += 64) {
        __syncthreads();
#pragma unroll
        for (int kh = 0; kh < 2; ++kh) {
            const int kk = k0 + kh * 32;
            GLDS(A + (size_t)(bm * 128 + g_row) * K + kk + g_col,      As[kh] + wave * 512);
            GLDS(A + (size_t)(bm * 128 + g_row + 64) * K + kk + g_col, As[kh] + wave * 512 + 2048);
            GLDS(B + (size_t)(bn * 128 + g_row) * K + kk + g_col,      Bs[kh] + wave * 512);
            GLDS(B + (size_t)(bn * 128 + g_row + 64) * K + kk + g_col, Bs[kh] + wave * 512 + 2048);
        }
        __syncthreads();

#pragma unroll
        for (int kh = 0; kh < 2; ++kh) {
            short8 a[4], b[4];
#pragma unroll
            for (int i = 0; i < 4; ++i)
                a[i] = *(const short8*)(As[kh] + (wr + i * 16 + lrow) * 32 + quad * 8);
#pragma unroll
            for (int j = 0; j < 4; ++j)
                b[j] = *(const short8*)(Bs[kh] + (wc + j * 16 + lrow) * 32 + quad * 8);
#pragma unroll
            for (int i = 0; i < 4; ++i)
#pragma unroll
                for (int j = 0; j < 4; ++j)
                    acc[i][j] = __builtin_amdgcn_mfma_f32_16x16x32_bf16(a[i], b[j], acc[i][j], 0, 0, 0);
        }
    }

    if (cm == 2) {
        __syncthreads();
        uint16_t* scr = As[0] + wave * 1024;
#pragma unroll
        for (int i = 0; i < 4; ++i)
#pragma unroll
            for (int j = 0; j < 4; ++j) {
                uint2 pk;
                pk.x = (uint32_t)f2bf(acc[i][j][0]) | ((uint32_t)f2bf(acc[i][j][1]) << 16);
                pk.y = (uint32_t)f2bf(acc[i][j][2]) | ((uint32_t)f2bf(acc[i][j][3]) << 16);
                *(uint2*)(scr + lrow * 16 + quad * 4) = pk;
                if (lane < 32) {
                    int n = lane >> 1, m8 = (lane & 1) * 8;
                    short8 vv = *(const short8*)(scr + n * 16 + m8);
                    int ng = bn * 128 + wc + j * 16 + n;        // (h,d)
                    int hh = ng >> 6, d = ng & 63;
                    int mg = bm * 128 + wr + i * 16;            // t base
                    int bb = mg >> 10, tl = (mg & 1023) + m8;
                    *(short8*)(C + ((((size_t)bb * 16 + hh) * 64 + d) * 1024 + tl)) = vv;
                }
            }
        return;
    }

#pragma unroll
    for (int i = 0; i < 4; ++i)
#pragma unroll
        for (int j = 0; j < 4; ++j)
#pragma unroll
            for (int r = 0; r < 4; ++r) {
                // verified C/D map: row = quad*4 + reg, col = lane&15
                int m = bm * 128 + wr + i * 16 + quad * 4 + r;
                int n = bn * 128 + wc + j * 16 + lrow;
                int bb = m >> 10, tt = m & 1023, hh = n >> 6, d = n & 63;
                C[(((size_t)bb * 16 + hh) * 1024 + tt) * 64 + d] = f2bf(acc[i][j][r]);
            }
}

// ---------------------------------------------------------------------------
// Output projection, 64x128 tiles (512 blocks = 2/CU), BK=64 two-half
// staging (same rationale as qkv). Waves 2x2 of 32x64; 16 MFMA/iter.
// LDS 24KB.
// ---------------------------------------------------------------------------
__global__ __launch_bounds__(256) void gemm_out(
    const uint16_t* __restrict__ A, const uint16_t* __restrict__ B,
    float* __restrict__ C, int M, int N, int K)
{
    __shared__ alignas(16) uint16_t As[2][64 * 32];
    __shared__ alignas(16) uint16_t Bs[2][128 * 32];

    const int t = threadIdx.x;
    const int lane = t & 63, wave = t >> 6;
    const int lrow = lane & 15, quad = lane >> 4;
    const int wr = (wave >> 1) * 32, wc = (wave & 1) * 64;
    const int g_row = wave * 16 + (lane >> 2);
    const int g_col = (lane & 3) * 8;
    const int bm = blockIdx.x, bn = blockIdx.y;

    const f32x4 fz = {0.f, 0.f, 0.f, 0.f};
    f32x4 acc[2][4];
#pragma unroll
    for (int i = 0; i < 2; ++i)
#pragma unroll
        for (int j = 0; j < 4; ++j) acc[i][j] = fz;

    for (int k0 = 0; k0 < K; k0 += 64) {
        __syncthreads();
#pragma unroll
        for (int kh = 0; kh < 2; ++kh) {
            const int kk = k0 + kh * 32;
            GLDS(A + (size_t)(bm * 64 + g_row) * K + kk + g_col,       As[kh] + wave * 512);
            GLDS(B + (size_t)(bn * 128 + g_row) * K + kk + g_col,      Bs[kh] + wave * 512);
            GLDS(B + (size_t)(bn * 128 + g_row + 64) * K + kk + g_col, Bs[kh] + wave * 512 + 2048);
        }
        __syncthreads();

#pragma unroll
        for (int kh = 0; kh < 2; ++kh) {
            short8 a[2], b[4];
#pragma unroll
            for (int i = 0; i < 2; ++i)
                a[i] = *(const short8*)(As[kh] + (wr + i * 16 + lrow) * 32 + quad * 8);
#pragma unroll
            for (int j = 0; j < 4; ++j)
                b[j] = *(const short8*)(Bs[kh] + (wc + j * 16 + lrow) * 32 + quad * 8);
#pragma unroll
            for (int i = 0; i < 2; ++i)
#pragma unroll
                for (int j = 0; j < 4; ++j)
                    acc[i][j] = __builtin_amdgcn_mfma_f32_16x16x32_bf16(a[i], b[j], acc[i][j], 0, 0, 0);
        }
    }

#pragma unroll
    for (int i = 0; i < 2; ++i)
#pragma unroll
        for (int j = 0; j < 4; ++j)
#pragma unroll
            for (int r = 0; r < 4; ++r) {
                int m = bm * 64 + wr + i * 16 + quad * 4 + r;
                int n = bn * 128 + wc + j * 16 + lrow;
                C[(size_t)m * N + n] = acc[i][j][r];
            }
}

// ---------------------------------------------------------------------------
// Flash attention v7 (UNCHANGED from round 12 — locally converged at ~82.7us
// after 6 structural rounds; dbuf K/V staging, 1 barrier/iter, Pl stride 72,
// band/const split, fixed-max softmax).
// LDS: Ks 16K + Vs 16K + Qpos_l 35K + Pl 9K = 77 KB -> 2 blocks/CU.
// Qpos_l row width MUST be >= 272 (prologue writes cols up to 271).
// ---------------------------------------------------------------------------
__global__ __launch_bounds__(256) void flash_attn(
    const uint16_t* __restrict__ Qh, const uint16_t* __restrict__ Kh,
    const uint16_t* __restrict__ Vt, const uint16_t* __restrict__ pos,
    const int* __restrict__ mask, uint16_t* __restrict__ comb)
{
    const int blk = blockIdx.x;     // 0..1023
    const int bh = blk >> 4;        // b*16+h
    const int qt = blk & 15;
    const int b = bh >> 4;
    const int h = bh & 15;
    const int t = threadIdx.x;
    const int lane = t & 63;
    const int wave = t >> 6;
    const int lrow = lane & 15;
    const int quad = lane >> 4;
    const int qb = qt * 64 + wave * 16;

    __shared__ alignas(16) uint16_t Ks[2][4096];       // 2 x 8 KB
    __shared__ alignas(16) uint16_t Vs[2][4096];       // 2 x 8 KB
    __shared__ alignas(16) uint16_t Qpos_l[64][274];   // 35072 B
    __shared__ alignas(16) uint16_t Pl[4][16][72];     // 9216 B

    const uint16_t* Kp = Kh + (size_t)bh * 65536;
    const uint16_t* Vp = Vt + (size_t)bh * 65536;
    const int* mk = mask + b * 1024;

    const int sg_r = lane >> 2;
    const int sg_c = (lane & 3) * 8;
    const int hw = wave >> 1;
    const int gw = (wave & 1) * 2;

    // issue tile-0 staging first: latency hides under the pos-slab prologue
#pragma unroll
    for (int gg = 0; gg < 2; ++gg) {
        int g = gw + gg;
        GLDS(Kp + (size_t)(g * 16 + sg_r) * 64 + hw * 32 + sg_c, &Ks[0][hw * 2048 + g * 512]);
        GLDS(Vp + (size_t)(g * 16 + sg_r) * 1024 + hw * 32 + sg_c, &Vs[0][hw * 2048 + g * 512]);
    }

    const uint16_t* Qp = Qh + ((size_t)bh * 1024 + qb) * 64;
    short8 aq0 = *(const short8*)(Qp + (size_t)lrow * 64 + quad * 8);
    short8 aq1 = *(const short8*)(Qp + (size_t)lrow * 64 + 32 + quad * 8);

    const f32x4 fz = {0.f, 0.f, 0.f, 0.f};

    // ---- prologue: 16x272 pos-logit slab, B-frags from global (L2-hot) ----
#pragma unroll 4
    for (int nt = 0; nt < 17; ++nt) {
        short8 pb0 = *(const short8*)(pos + (size_t)(nt * 16 + lrow) * 64 + quad * 8);
        short8 pb1 = *(const short8*)(pos + (size_t)(nt * 16 + lrow) * 64 + 32 + quad * 8);
        f32x4 c = __builtin_amdgcn_mfma_f32_16x16x32_bf16(aq0, pb0, fz, 0, 0, 0);
        c = __builtin_amdgcn_mfma_f32_16x16x32_bf16(aq1, pb1, c, 0, 0, 0);
#pragma unroll
        for (int r = 0; r < 4; ++r)
            Qpos_l[wave * 16 + quad * 4 + r][nt * 16 + lrow] = f2bf(c[r]);
    }

    float pcl[4], pch[4];
#pragma unroll
    for (int r = 0; r < 4; ++r) {
        int ql = wave * 16 + quad * 4 + r;
        pcl[r] = bf2f(Qpos_l[ql][0])   * 0.125f;
        pch[r] = bf2f(Qpos_l[ql][256]) * 0.125f;
    }

    f32x4 o[4] = {fz, fz, fz, fz};
    float lsum[4] = {0.f, 0.f, 0.f, 0.f};

    for (int kb = 0; kb < 1024; kb += 64) {
        const int cur = (kb >> 6) & 1;
        __syncthreads();  // drains prefetch (issued last iter); guards buffers
        if (kb + 64 < 1024) {
            const int nxt = cur ^ 1;
#pragma unroll
            for (int gg = 0; gg < 2; ++gg) {
                int g = gw + gg;
                GLDS(Kp + (size_t)(kb + 64 + g * 16 + sg_r) * 64 + hw * 32 + sg_c,
                     &Ks[nxt][hw * 2048 + g * 512]);
                GLDS(Vp + (size_t)(g * 16 + sg_r) * 1024 + kb + 64 + hw * 32 + sg_c,
                     &Vs[nxt][hw * 2048 + g * 512]);
            }
        }
        const uint16_t* Kc = Ks[cur];
        const uint16_t* Vc = Vs[cur];

        f32x4 s[4];
#pragma unroll
        for (int j = 0; j < 4; ++j) {
            short8 k0 = *(const short8*)(Kc + (j * 16 + lrow) * 32 + quad * 8);
            short8 k1 = *(const short8*)(Kc + 2048 + (j * 16 + lrow) * 32 + quad * 8);
            s[j] = __builtin_amdgcn_mfma_f32_16x16x32_bf16(aq0, k0, fz, 0, 0, 0);
            s[j] = __builtin_amdgcn_mfma_f32_16x16x32_bf16(aq1, k1, s[j], 0, 0, 0);
        }

        const int diff = kb - qb;                    // wave-uniform
        if (diff <= -192 || diff >= 144) {
            const bool low = (diff <= -192);
#pragma unroll
            for (int j = 0; j < 4; ++j) {
                const int key = kb + j * 16 + lrow;
                const bool m = (mk[key] != 0);
#pragma unroll
                for (int r = 0; r < 4; ++r) {
                    float pc = low ? pcl[r] : pch[r];
                    float e = m ? 0.f : __expf(__builtin_fmaf(s[j][r], 0.125f, pc));
                    lsum[r] += e;
                    Pl[wave][quad * 4 + r][j * 16 + lrow] = f2bf(e);
                }
            }
        } else {
#pragma unroll
            for (int j = 0; j < 4; ++j) {
                const int key = kb + j * 16 + lrow;
                const bool m = (mk[key] != 0);
#pragma unroll
                for (int r = 0; r < 4; ++r) {
                    int q = qb + quad * 4 + r;
                    int ql = q & 63;
                    int rel = min(max(key - q, -128), 128) + 128;
                    float p = bf2f(Qpos_l[ql][rel]);
                    float e = m ? 0.f : __expf((s[j][r] + p) * 0.125f);
                    lsum[r] += e;
                    Pl[wave][quad * 4 + r][j * 16 + lrow] = f2bf(e);
                }
            }
        }
        short8 ap0 = *(const short8*)(&Pl[wave][lrow][quad * 8]);
        short8 ap1 = *(const short8*)(&Pl[wave][lrow][32 + quad * 8]);

#pragma unroll
        for (int dt = 0; dt < 4; ++dt) {
            short8 v0 = *(const short8*)(Vc + (dt * 16 + lrow) * 32 + quad * 8);
            short8 v1 = *(const short8*)(Vc + 2048 + (dt * 16 + lrow) * 32 + quad * 8);
            o[dt] = __builtin_amdgcn_mfma_f32_16x16x32_bf16(ap0, v0, o[dt], 0, 0, 0);
            o[dt] = __builtin_amdgcn_mfma_f32_16x16x32_bf16(ap1, v1, o[dt], 0, 0, 0);
        }
    }

#pragma unroll
    for (int off = 1; off < 16; off <<= 1)
#pragma unroll
        for (int r = 0; r < 4; ++r)
            lsum[r] += __shfl_xor(lsum[r], off);

    float inv[4];
#pragma unroll
    for (int r = 0; r < 4; ++r) inv[r] = 1.0f / lsum[r];

#pragma unroll
    for (int dt = 0; dt < 4; ++dt)
#pragma unroll
        for (int r = 0; r < 4; ++r) {
            size_t row = (size_t)b * 1024 + qb + quad * 4 + r;
            size_t col = (size_t)h * 64 + dt * 16 + lrow;
            comb[row * 1024 + col] = f2bf(o[dt][r] * inv[r]);
        }
}

// ---------------------------------------------------------------------------
// ws layout (hard-coded "big" path, ~56.1 MB; ws_size >= ~72 MB evidenced by
// rounds 0-3 which used 72+ MB layouts without fault):
// Qh 8 | Khd 8 | Vt 8 | xqb 8 (comb reuse) | xkb 8 | xvb 8 | W*4 8 | posb | canon
// ---------------------------------------------------------------------------
extern "C" void kernel_launch(void* const* d_in, const int* in_sizes, int n_in,
                              void* d_out, int out_size, void* d_ws, size_t ws_size,
                              hipStream_t stream)
{
    const float* x_q = (const float*)d_in[0];
    const float* x_k = (const float*)d_in[1];
    const float* x_v = (const float*)d_in[2];
    const void*  msk = d_in[3];
    const float* Wq  = (const float*)d_in[4];
    const float* Wk  = (const float*)d_in[5];
    const float* Wv  = (const float*)d_in[6];
    const float* Wo  = (const float*)d_in[7];
    const float* pos = (const float*)d_in[8];

    char* ws = (char*)d_ws;
    const size_t MB = 1u << 20;
    uint16_t* Qh   = (uint16_t*)(ws);
    uint16_t* Khd  = (uint16_t*)(ws + 8 * MB);
    uint16_t* Vt   = (uint16_t*)(ws + 16 * MB);
    uint16_t* xqb  = (uint16_t*)(ws + 24 * MB);
    uint16_t* xkb  = (uint16_t*)(ws + 32 * MB);
    uint16_t* xvb  = (uint16_t*)(ws + 40 * MB);
    uint16_t* Wqb  = (uint16_t*)(ws + 48 * MB);
    uint16_t* Wkb  = (uint16_t*)(ws + 50 * MB);
    uint16_t* Wvb  = (uint16_t*)(ws + 52 * MB);
    uint16_t* Wob  = (uint16_t*)(ws + 54 * MB);
    uint16_t* posb = (uint16_t*)(ws + 56 * MB);       // 272x64 bf16, rows 257+ zero
    int*      canon = (int*)(ws + 56 * MB + 65536);
    uint16_t* comb = xqb;  // xqb dead after projections; flash runs after them

    CvtArgs ca{};
    int ns = 0;
    ca.seg[ns++] = {x_q, xqb, 524288};
    ca.seg[ns++] = {x_k, xkb, 524288};
    ca.seg[ns++] = {x_v, xvb, 524288};
    ca.seg[ns++] = {Wq, Wqb, 131072};
    ca.seg[ns++] = {Wk, Wkb, 131072};
    ca.seg[ns++] = {Wv, Wvb, 131072};
    ca.seg[ns++] = {Wo, Wob, 131072};
    ca.seg[ns++] = {pos, posb, 2056};              // 257*64/8
    ca.seg[ns++] = {nullptr, posb + 16448, 120};   // zero rows 257..271
    ca.nseg = ns;
    ca.mraw = msk;
    ca.mcanon = canon;
    cvt_bf16<<<dim3(512), dim3(256), 0, stream>>>(ca);

    // Fused Q/K/V projections, BK=64 two-half staging: 32x8x3 = 768 blocks
    gemm128_qkv<<<dim3(32, 8, 3), dim3(256), 0, stream>>>(
        xqb, xkb, xvb, Wqb, Wkb, Wvb, Qh, Khd, Vt);

    flash_attn<<<dim3(1024), dim3(256), 0, stream>>>(Qh, Khd, Vt, posb, canon, comb);

    // Output projection: comb(bf16) @ Wo_b^T -> fp32 d_out (64x128, BK=64)
    gemm_out<<<dim3(64, 8), dim3(256), 0, stream>>>(
        comb, Wob, (float*)d_out, 4096, 1024, 1024);
}